// Round 3
// baseline (8894.732 us; speedup 1.0000x reference)
//
#include <hip/hip_runtime.h>

#define BDIM 256   // batch
#define SDIM 512   // seq len
#define HDIM 512   // hidden
#define VDIM 128   // vocab
#define NBG 8      // batch groups
#define BB 32      // batch per group
#define HHU 16     // hidden units per block
#define KP 520     // padded LDS pitch for K=512 (bf16 elems)
#define WIHP 136   // padded pitch for W_ih slice
#define NT 320     // threads per block (5 waves)
#define QPR 256    // qwords per batch row (2 h + tag per 8B qword)
#define SLOTS (BB * QPR)  // 8192 qwords staged per step

typedef unsigned short ushort_t;
typedef unsigned long long u64_t;
typedef __attribute__((ext_vector_type(8))) short bf16x8;
typedef __attribute__((ext_vector_type(4))) float f32x4;

__device__ __forceinline__ ushort_t f2bf(float x) {
  unsigned u = __builtin_bit_cast(unsigned, x);
  u += 0x7fffu + ((u >> 16) & 1u);
  return (ushort_t)(u >> 16);
}
__device__ __forceinline__ float bf2f(ushort_t b) {
  unsigned u = ((unsigned)b) << 16;
  return __builtin_bit_cast(float, u);
}
__device__ __forceinline__ float sigmoidf_(float x) { return 1.f / (1.f + __expf(-x)); }
__device__ __forceinline__ float tanhf_(float x) { return 2.f / (1.f + __expf(-2.f * x)) - 1.f; }

__device__ __forceinline__ void pack_store8(ushort_t* dst, const float* s) {
  ushort_t tmp[8];
#pragma unroll
  for (int j = 0; j < 8; ++j) tmp[j] = f2bf(s[j]);
  uint4 v;
  v.x = (unsigned)tmp[0] | ((unsigned)tmp[1] << 16);
  v.y = (unsigned)tmp[2] | ((unsigned)tmp[3] << 16);
  v.z = (unsigned)tmp[4] | ((unsigned)tmp[5] << 16);
  v.w = (unsigned)tmp[6] | ((unsigned)tmp[7] << 16);
  *(uint4*)dst = v;
}

// A-operand fragments (weights) in VGPRs: lane m=lane&15 holds row m, k-octet ko.
__device__ __forceinline__ void load_afrag(bf16x8* af, const float* W, int gr, int ko,
                                           bool valid) {
  const float* row = W + (size_t)gr * HDIM;
#pragma unroll
  for (int kt = 0; kt < 16; ++kt) {
    bf16x8 v;
    if (valid) {
      const float4 f0 = *(const float4*)(row + kt * 32 + ko);
      const float4 f1 = *(const float4*)(row + kt * 32 + ko + 4);
      v[0] = (short)f2bf(f0.x); v[1] = (short)f2bf(f0.y);
      v[2] = (short)f2bf(f0.z); v[3] = (short)f2bf(f0.w);
      v[4] = (short)f2bf(f1.x); v[5] = (short)f2bf(f1.y);
      v[6] = (short)f2bf(f1.z); v[7] = (short)f2bf(f1.w);
    } else {
#pragma unroll
      for (int j = 0; j < 8; ++j) v[j] = 0;
    }
    af[kt] = v;
  }
}

// W_ih slice + bias, rows ordered L = unit_local*4 + gate (matches MFMA C rows).
__device__ __forceinline__ void load_wih(ushort_t* Wih_s, float* bias_s, const float* Wih,
                                         const float* bi, const float* bh, int hs, int tid) {
  for (int c = tid; c < 64 * 16; c += NT) {
    int L = c >> 4, k8 = (c & 15) * 8;
    int gr = (L & 3) * HDIM + hs * HHU + (L >> 2);
    pack_store8(&Wih_s[L * WIHP + k8], Wih + (size_t)gr * VDIM + k8);
  }
  if (tid < 64) {
    int gr = (tid & 3) * HDIM + hs * HHU + (tid >> 2);
    bias_s[tid] = bi[gr] + bh[gr];
  }
}

// Sync: h published as 8B relaxed agent-scope qwords (h_2j | h_2j+1<<16 | tag<<48).
// tag visible => producer's step complete (value is data-dependent on all its reads).
// Consumer spins per-thread on its own 26 qwords, unpacks to LDS as they validate,
// then ONE __syncthreads. No flags, no vmcnt(0) drain, no cache-wide fences.
__global__ void __launch_bounds__(NT, 1) lstm_kernel(
    const int* __restrict__ C_idx, const int* __restrict__ E,
    const float* __restrict__ eWih, const float* __restrict__ eWhh,
    const float* __restrict__ ebi, const float* __restrict__ ebh,
    const float* __restrict__ dWih, const float* __restrict__ dWhh,
    const float* __restrict__ dbi, const float* __restrict__ dbh,
    const float* __restrict__ pW, const float* __restrict__ pb,
    u64_t* hbq, ushort_t* logits) {
  __shared__ ushort_t h_s[BB * KP];
  __shared__ ushort_t Wih_s[64 * WIHP];
  __shared__ float bias_s[64];
  __shared__ float pb_s[4];
  __shared__ int idx_s[2][BB];

  const int tid = threadIdx.x;
  const int w = tid >> 6;
  const int lane = tid & 63;
  const int m = lane & 15;        // A row / C col-batch index
  const int quad = lane >> 4;     // k-octet / C row-quad (unit within wave)
  const int ko = quad * 8;
  const int bg = blockIdx.x & 7;  // one batch group per XCD under round-robin
  const int hs = blockIdx.x >> 3;

  // persistent per-lane state: weights fragments + cell state
  bf16x8 afrag[16];
  if (w < 4) {
    int grA = (m & 3) * HDIM + hs * HHU + w * 4 + (m >> 2);
    load_afrag(afrag, eWhh, grA, ko, true);
  } else {
    load_afrag(afrag, pW, hs * 4 + m, ko, m < 4);
  }
  float c0 = 0.f, c1 = 0.f;

  load_wih(Wih_s, bias_s, eWih, ebi, ebh, hs, tid);
  if (tid < 4) pb_s[tid] = pb[hs * 4 + tid];
  if (tid < BB) idx_s[0][tid] = C_idx[(size_t)(bg * BB + tid) * SDIM];
  __syncthreads();

  for (int t = 0; t <= 1024; ++t) {
    const bool last = (t == 1024);
    const bool proj_on = (t >= 513);

    // prefetch idx for step t+1 (issue load now, LDS-write after spin)
    int myidx = 0;
    const bool pf = (tid < BB) && (t + 1 < 1024);
    if (pf) {
      int tn = t + 1;
      myidx = (tn >= 512) ? E[(size_t)(bg * BB + tid) * (SDIM + 1) + (tn - 512)]
                          : C_idx[(size_t)(bg * BB + tid) * SDIM + tn];
    }
    // decoder weight fragments (registers, per-wave; latency hidden behind spin)
    if (t == 512 && w < 4) {
      int grA = (m & 3) * HDIM + hs * HHU + w * 4 + (m >> 2);
      load_afrag(afrag, dWhh, grA, ko, true);
    }

    // spin-validate-stage: each thread owns up to 26 qwords of h(t)
    {
      const u64_t* src = hbq + ((size_t)(t & 1) * BDIM + bg * BB) * QPR;
      unsigned inv = (tid + 25 * NT < SLOTS) ? 0x3FFFFFFu : 0x1FFFFFFu;
      const unsigned tagexp = (unsigned)t;
      int rounds = 0;
      while (inv) {
        u64_t tmp[26];
#pragma unroll
        for (int k = 0; k < 26; ++k)
          if (inv & (1u << k))
            tmp[k] = __hip_atomic_load(src + tid + k * NT, __ATOMIC_RELAXED,
                                       __HIP_MEMORY_SCOPE_AGENT);
#pragma unroll
        for (int k = 0; k < 26; ++k)
          if (inv & (1u << k)) {
            u64_t q = tmp[k];
            if ((unsigned)(q >> 48) == tagexp) {
              int c = tid + k * NT;
              *(unsigned*)&h_s[(c >> 8) * KP + (c & 255) * 2] = (unsigned)q;
              inv &= ~(1u << k);
            }
          }
        if (inv) __builtin_amdgcn_s_sleep(1);
        if (++rounds > (1 << 18)) break;  // bailout (never hit if co-resident)
      }
    }
    if (pf) idx_s[(t + 1) & 1][tid] = myidx;
    if (t == 512) load_wih(Wih_s, bias_s, dWih, dbi, dbh, hs, tid);
    __syncthreads();  // h_s complete; all producers (hence all prior readers) done

    if ((w < 4 && !last) || (w == 4 && proj_on)) {
      f32x4 acc0 = {0.f, 0.f, 0.f, 0.f};
      f32x4 acc1 = {0.f, 0.f, 0.f, 0.f};
      if (w < 4) {
        const int L = w * 16 + quad * 4;
        const int i0 = idx_s[t & 1][m], i1 = idx_s[t & 1][16 + m];
#pragma unroll
        for (int r = 0; r < 4; ++r) {
          float bv = bias_s[L + r];
          acc0[r] = bv + bf2f(Wih_s[(L + r) * WIHP + i0]);
          acc1[r] = bv + bf2f(Wih_s[(L + r) * WIHP + i1]);
        }
      }
      const ushort_t* bp0 = &h_s[m * KP + ko];
      const ushort_t* bp1 = &h_s[(16 + m) * KP + ko];
#pragma unroll
      for (int kt = 0; kt < 16; ++kt) {
        bf16x8 bb0 = *(const bf16x8*)(bp0 + kt * 32);
        bf16x8 bb1 = *(const bf16x8*)(bp1 + kt * 32);
        acc0 = __builtin_amdgcn_mfma_f32_16x16x32_bf16(afrag[kt], bb0, acc0, 0, 0, 0);
        acc1 = __builtin_amdgcn_mfma_f32_16x16x32_bf16(afrag[kt], bb1, acc1, 0, 0, 0);
      }
      if (w < 4) {
        // acc0[r] = gate r of (batch m, unit w*4+quad); acc1 = batch 16+m
        float cn0 = sigmoidf_(acc0[1]) * c0 + sigmoidf_(acc0[0]) * tanhf_(acc0[2]);
        float cn1 = sigmoidf_(acc1[1]) * c1 + sigmoidf_(acc1[0]) * tanhf_(acc1[2]);
        c0 = cn0;
        c1 = cn1;
        float h0 = sigmoidf_(acc0[3]) * tanhf_(cn0);
        float h1 = sigmoidf_(acc1[3]) * tanhf_(cn1);
        unsigned hv0 = f2bf(h0), hv1 = f2bf(h1);
        unsigned po0 = (unsigned)__shfl_xor((int)hv0, 16);
        unsigned po1 = (unsigned)__shfl_xor((int)hv1, 16);
        const u64_t tag = ((u64_t)(unsigned)(t + 1)) << 48;
        const size_t jj = (size_t)hs * 8 + w * 2 + (quad >> 1);
        const size_t rbase = (size_t)(((t + 1) & 1)) * BDIM + bg * BB;
        if (!(quad & 1)) {  // even unit: store batch m's qword (me=lo, partner=hi)
          u64_t qw = (u64_t)hv0 | ((u64_t)po0 << 16) | tag;
          __hip_atomic_store(hbq + (rbase + m) * QPR + jj, qw, __ATOMIC_RELAXED,
                             __HIP_MEMORY_SCOPE_AGENT);
        } else {  // odd unit: store batch 16+m's qword (partner=lo, me=hi)
          u64_t qw = (u64_t)po1 | ((u64_t)hv1 << 16) | tag;
          __hip_atomic_store(hbq + (rbase + 16 + m) * QPR + jj, qw, __ATOMIC_RELAXED,
                             __HIP_MEMORY_SCOPE_AGENT);
        }
      } else if (quad == 0) {  // proj: rows 0..3 = vocab cols hs*4..hs*4+3
        const int ld = t - 513;
        u64_t q0 = 0, q1 = 0;
#pragma unroll
        for (int r = 0; r < 4; ++r) {
          q0 |= (u64_t)f2bf(acc0[r] + pb_s[r]) << (16 * r);
          q1 |= (u64_t)f2bf(acc1[r] + pb_s[r]) << (16 * r);
        }
        u64_t* lq = (u64_t*)logits;
        const size_t base = ((size_t)ld * BDIM + bg * BB) * 32 + hs;
        lq[base + (size_t)m * 32] = q0;
        lq[base + (size_t)(16 + m) * 32] = q1;
      }
    }
  }
}

__global__ void loss_kernel(const ushort_t* __restrict__ logits, const int* __restrict__ E,
                            float* __restrict__ partial) {
  const int t = blockIdx.x;   // 512
  const int b = threadIdx.x;  // 256
  const ushort_t* row = logits + ((size_t)t * BDIM + b) * VDIM;
  float mx = -3.0e38f;
  for (int k = 0; k < VDIM; ++k) mx = fmaxf(mx, bf2f(row[k]));
  float se = 0.f;
  for (int k = 0; k < VDIM; ++k) se += __expf(bf2f(row[k]) - mx);
  const int tgt = E[(size_t)b * (SDIM + 1) + t];
  float nll = (mx + __logf(se)) - bf2f(row[tgt]);
  float m = (tgt != 0) ? 1.f : 0.f;
  __shared__ float s1[BDIM];
  __shared__ float s0[BDIM];
  s1[b] = nll * m;
  s0[b] = m;
  __syncthreads();
  for (int s = 128; s > 0; s >>= 1) {
    if (b < s) {
      s1[b] += s1[b + s];
      s0[b] += s0[b + s];
    }
    __syncthreads();
  }
  if (b == 0) partial[t] = (s0[0] > 0.f) ? s1[0] / s0[0] : 0.f;
}

__global__ void reduce_kernel(const float* __restrict__ partial, float* __restrict__ out) {
  __shared__ float sm[SDIM];
  sm[threadIdx.x] = partial[threadIdx.x];
  __syncthreads();
  for (int s = 256; s > 0; s >>= 1) {
    if (threadIdx.x < s) sm[threadIdx.x] += sm[threadIdx.x + s];
    __syncthreads();
  }
  if (threadIdx.x == 0) out[0] = sm[0];
}

extern "C" void kernel_launch(void* const* d_in, const int* in_sizes, int n_in,
                              void* d_out, int out_size, void* d_ws, size_t ws_size,
                              hipStream_t stream) {
  const int* C_idx = (const int*)d_in[0];
  const int* E = (const int*)d_in[1];
  const float* eWih = (const float*)d_in[2];
  const float* eWhh = (const float*)d_in[3];
  const float* ebi = (const float*)d_in[4];
  const float* ebh = (const float*)d_in[5];
  const float* dWih = (const float*)d_in[6];
  const float* dWhh = (const float*)d_in[7];
  const float* dbi = (const float*)d_in[8];
  const float* dbh = (const float*)d_in[9];
  const float* pW = (const float*)d_in[10];
  const float* pb = (const float*)d_in[11];

  char* ws = (char*)d_ws;
  u64_t* hbq = (u64_t*)ws;                              // 2*256*256*8 = 1 MiB
  ushort_t* logits = (ushort_t*)(ws + 1048576);         // 512*256*128*2 = 32 MiB
  float* partial = (float*)(ws + 1048576 + 33554432);   // 512*4 B

  // zero h buffer 0 (h(0)=0, tags=0); buffer 1 validated by tag, no init needed
  hipMemsetAsync(d_ws, 0, 524288, stream);
  lstm_kernel<<<256, NT, 0, stream>>>(C_idx, E, eWih, eWhh, ebi, ebh, dWih, dWhh, dbi, dbh,
                                      pW, pb, hbq, logits);
  loss_kernel<<<512, 256, 0, stream>>>(logits, E, partial);
  reduce_kernel<<<1, 512, 0, stream>>>(partial, (float*)d_out);
}

// Round 4
// 3764.785 us; speedup vs baseline: 2.3626x; 2.3626x over previous
//
#include <hip/hip_runtime.h>

#define BDIM 256   // batch
#define SDIM 512   // seq len
#define HDIM 512   // hidden
#define VDIM 128   // vocab
#define NBG 8      // batch groups
#define BB 32      // batch per group
#define HHU 16     // hidden units per block
#define WIHP 72    // col-major W_ih pitch (halfwords) per vocab row
#define NT 320     // threads per block (5 waves)

typedef unsigned short ushort_t;
typedef unsigned long long u64_t;
typedef __attribute__((ext_vector_type(8))) short bf16x8;
typedef __attribute__((ext_vector_type(4))) float f32x4;
typedef __attribute__((ext_vector_type(16))) float f32x16;

__device__ __forceinline__ ushort_t f2bf(float x) {
  unsigned u = __builtin_bit_cast(unsigned, x);
  u += 0x7fffu + ((u >> 16) & 1u);
  return (ushort_t)(u >> 16);
}
__device__ __forceinline__ float bf2f(ushort_t b) {
  unsigned u = ((unsigned)b) << 16;
  return __builtin_bit_cast(float, u);
}
__device__ __forceinline__ float sigmoidf_(float x) { return 1.f / (1.f + __expf(-x)); }
__device__ __forceinline__ float tanhf_(float x) { return 2.f / (1.f + __expf(-2.f * x)) - 1.f; }

// ---- weight loading -------------------------------------------------------
// Gate A-fragments for mfma_32x32x16: lane m=lane&31 holds A row m, k-octet
// half=lane>>5. Row m decodes (g=m&3, h=(m>>2)&1, s=m>>3) -> unit 2s+h.
__device__ __forceinline__ void load_afrag32(bf16x8* af, const float* Whh, int hs, int w,
                                             int lane) {
  const int m = lane & 31, half = lane >> 5;
  const int g = m & 3, hh = (m >> 2) & 1, s = m >> 3;
  const int gr = g * HDIM + hs * HHU + w * 8 + 2 * s + hh;
  const float* row = Whh + (size_t)gr * HDIM + half * 8;
#pragma unroll
  for (int kt = 0; kt < 32; ++kt) {
    const float4 f0 = *(const float4*)(row + kt * 16);
    const float4 f1 = *(const float4*)(row + kt * 16 + 4);
    bf16x8 v;
    v[0] = (short)f2bf(f0.x); v[1] = (short)f2bf(f0.y);
    v[2] = (short)f2bf(f0.z); v[3] = (short)f2bf(f0.w);
    v[4] = (short)f2bf(f1.x); v[5] = (short)f2bf(f1.y);
    v[6] = (short)f2bf(f1.z); v[7] = (short)f2bf(f1.w);
    af[kt] = v;
  }
}
// Proj A-fragments for mfma_16x16x32 (rows 0..3 valid = vocab hs*4+m).
__device__ __forceinline__ void load_afrag16(bf16x8* af, const float* W, int gr, int ko,
                                             bool valid) {
  const float* row = W + (size_t)gr * HDIM;
#pragma unroll
  for (int kt = 0; kt < 16; ++kt) {
    bf16x8 v;
    if (valid) {
      const float4 f0 = *(const float4*)(row + kt * 32 + ko);
      const float4 f1 = *(const float4*)(row + kt * 32 + ko + 4);
      v[0] = (short)f2bf(f0.x); v[1] = (short)f2bf(f0.y);
      v[2] = (short)f2bf(f0.z); v[3] = (short)f2bf(f0.w);
      v[4] = (short)f2bf(f1.x); v[5] = (short)f2bf(f1.y);
      v[6] = (short)f2bf(f1.z); v[7] = (short)f2bf(f1.w);
    } else {
#pragma unroll
      for (int j = 0; j < 8; ++j) v[j] = 0;
    }
    af[kt] = v;
  }
}
// W_ih column-major [vocab][64 gate-cols], col' = (w*2+h)*16 + s*4 + g, + bias.
__device__ __forceinline__ void load_wih_cm(ushort_t* wih_s, float* bias_s, const float* Wih,
                                            const float* bi, const float* bh, int hs,
                                            int tid) {
  for (int c = tid; c < 128 * 64; c += NT) {
    int v = c & 127, col = c >> 7;
    int g = col & 3, s = (col >> 2) & 3, hh = (col >> 4) & 1, wv = col >> 5;
    int gr = g * HDIM + hs * HHU + wv * 8 + 2 * s + hh;
    wih_s[v * WIHP + col] = f2bf(Wih[(size_t)gr * VDIM + v]);
  }
  if (tid < 64) {
    int col = tid;
    int g = col & 3, s = (col >> 2) & 3, hh = (col >> 4) & 1, wv = col >> 5;
    int gr = g * HDIM + hs * HHU + wv * 8 + 2 * s + hh;
    bias_s[col] = bi[gr] + bh[gr];
  }
}

// Sync: R2 flag protocol. Producers: relaxed agent h-stores -> __syncthreads
// (compiler drains vmcnt(0) before s_barrier) -> relaxed agent flag store.
// Consumers: 32 lanes poll 32 flags (one coalesced 128B load per round).
// h_s is XOR-swizzled at 16B-octet granularity: phys_octet = octet ^ (batch&7)
// -> ds_read_b128 B-fragments spread over all 32 banks (2/bank = free).
__global__ void __launch_bounds__(NT, 1) lstm_kernel(
    const int* __restrict__ C_idx, const int* __restrict__ E,
    const float* __restrict__ eWih, const float* __restrict__ eWhh,
    const float* __restrict__ ebi, const float* __restrict__ ebh,
    const float* __restrict__ dWih, const float* __restrict__ dWhh,
    const float* __restrict__ dbi, const float* __restrict__ dbh,
    const float* __restrict__ pW, const float* __restrict__ pb,
    unsigned* flags, u64_t* hbq, ushort_t* logits) {
  __shared__ ushort_t h_s[BB * HDIM];       // 32 KB, swizzled
  __shared__ ushort_t wih_s[VDIM * WIHP];   // 18 KB, col-major
  __shared__ float bias_s[64];
  __shared__ float pb_s[4];
  __shared__ int idx_s[2][BB];

  const int tid = threadIdx.x;
  const int w = tid >> 6;
  const int lane = tid & 63;
  const int bg = blockIdx.x & 7;  // one batch group per XCD under round-robin
  const int hs = blockIdx.x >> 3;

  // persistent per-lane state
  bf16x8 afrag[32];  // gate waves: 32 K-chunks (128 VGPR). proj wave: 16 used.
  float cst[4] = {0.f, 0.f, 0.f, 0.f};
  if (w < 2) {
    load_afrag32(afrag, eWhh, hs, w, lane);
  } else if (w == 4) {
    load_afrag16(afrag, pW, hs * 4 + (lane & 15), (lane >> 4) * 8, (lane & 15) < 4);
  }
  load_wih_cm(wih_s, bias_s, eWih, ebi, ebh, hs, tid);
  if (tid < 4) pb_s[tid] = pb[hs * 4 + tid];
  if (tid < BB) idx_s[0][tid] = C_idx[(size_t)(bg * BB + tid) * SDIM];
  __syncthreads();

  for (int t = 0; t <= 1024; ++t) {
    const bool last = (t == 1024);
    const bool proj_on = (t >= 513);

    if (t == 512) {  // phase switch (one-time cost, before this step's barrier)
      if (w < 2) load_afrag32(afrag, dWhh, hs, w, lane);
      load_wih_cm(wih_s, bias_s, dWih, dbi, dbh, hs, tid);
    }
    // prefetch idx for step t+1 (load now, LDS-write after stage barrier)
    int myidx = 0;
    const bool pf = (tid < BB) && (t + 1 < 1024);
    if (pf) {
      int tn = t + 1;
      myidx = (tn >= 512) ? E[(size_t)(bg * BB + tid) * (SDIM + 1) + (tn - 512)]
                          : C_idx[(size_t)(bg * BB + tid) * SDIM + tn];
    }

    // poll: all 32 producers of this bg finished step t-1
    if (t > 0 && w == 0 && lane < BB) {
      int rounds = 0;
      while (__hip_atomic_load(&flags[bg * BB + lane], __ATOMIC_RELAXED,
                               __HIP_MEMORY_SCOPE_AGENT) < (unsigned)t) {
        if (++rounds > (1 << 20)) break;  // bailout (never hit if co-resident)
      }
    }
    __syncthreads();

    // stage h[32,512] bf16 (4096 u64) -> swizzled LDS
    {
      const u64_t* src = hbq + ((size_t)(t & 1) * BDIM + bg * BB) * 128;
      u64_t tmp[13];
#pragma unroll
      for (int k = 0; k < 13; ++k) {
        int c = tid + k * NT;
        if (c < 4096)
          tmp[k] = __hip_atomic_load(src + c, __ATOMIC_RELAXED, __HIP_MEMORY_SCOPE_AGENT);
      }
#pragma unroll
      for (int k = 0; k < 13; ++k) {
        int c = tid + k * NT;
        if (c < 4096) {
          int m = c >> 7, k7 = c & 127;
          int p = (k7 >> 1) ^ (m & 7);
          *(u64_t*)&h_s[m * HDIM + p * 8 + (k7 & 1) * 4] = tmp[k];
        }
      }
    }
    __syncthreads();
    if (pf) idx_s[(t + 1) & 1][tid] = myidx;

    if (w < 2 && !last) {
      // gates: D[64 gate-rows x 32 batches] via 2 waves of mfma_32x32x16
      const int b = lane & 31, half = lane >> 5;
      const int w2h = w * 2 + half;
      f32x16 acc;
      {
        const int id0 = idx_s[t & 1][b];
        const ushort_t* wp = &wih_s[id0 * WIHP + w2h * 16];
        bf16x8 g0 = *(const bf16x8*)wp;
        bf16x8 g1 = *(const bf16x8*)(wp + 8);
#pragma unroll
        for (int r = 0; r < 8; ++r) {
          acc[r] = bias_s[w2h * 16 + r] + bf2f((ushort_t)g0[r]);
          acc[8 + r] = bias_s[w2h * 16 + 8 + r] + bf2f((ushort_t)g1[r]);
        }
      }
#pragma unroll
      for (int kt = 0; kt < 32; ++kt) {
        bf16x8 bfr = *(const bf16x8*)&h_s[b * HDIM + ((kt * 2 + half) ^ (b & 7)) * 8];
        acc = __builtin_amdgcn_mfma_f32_32x32x16_bf16(afrag[kt], bfr, acc, 0, 0, 0);
      }
      // acc[s*4+g] = gate g, unit 2s+half (of this wave's 8 units), batch b
      unsigned hv[4];
#pragma unroll
      for (int s = 0; s < 4; ++s) {
        float ig = acc[s * 4 + 0], fg = acc[s * 4 + 1];
        float gg = acc[s * 4 + 2], og = acc[s * 4 + 3];
        float cn = sigmoidf_(fg) * cst[s] + sigmoidf_(ig) * tanhf_(gg);
        cst[s] = cn;
        hv[s] = f2bf(sigmoidf_(og) * tanhf_(cn));
      }
      u64_t own = (u64_t)hv[0] | ((u64_t)hv[1] << 16) | ((u64_t)hv[2] << 32) |
                  ((u64_t)hv[3] << 48);
      u64_t par = (u64_t)__shfl_xor((long long)own, 32, 64);  // partner: half^1
      u64_t out = 0;
#pragma unroll
      for (int j = 0; j < 4; ++j) {  // pack units 4*half+j (j ascending)
        int u4 = 4 * half + j;
        int sidx = 2 * half + (j >> 1);
        u64_t sv = ((u4 & 1) == half) ? own : par;
        out |= ((sv >> (16 * sidx)) & 0xFFFFull) << (16 * j);
      }
      __hip_atomic_store(
          hbq + ((size_t)((t + 1) & 1) * BDIM + bg * BB + b) * 128 + hs * 4 + w * 2 + half,
          out, __ATOMIC_RELAXED, __HIP_MEMORY_SCOPE_AGENT);
    } else if (w == 4 && proj_on) {
      // proj: vocab rows hs*4..hs*4+3 x 32 batches, 2 tiles of mfma_16x16x32
      const int n = lane & 15, q = lane >> 4;
      f32x4 acc0 = {0.f, 0.f, 0.f, 0.f};
      f32x4 acc1 = {0.f, 0.f, 0.f, 0.f};
#pragma unroll
      for (int kt = 0; kt < 16; ++kt) {
        const int po = ((kt * 4 + q) ^ (n & 7)) * 8;
        bf16x8 b0 = *(const bf16x8*)&h_s[n * HDIM + po];
        bf16x8 b1 = *(const bf16x8*)&h_s[(16 + n) * HDIM + po];
        acc0 = __builtin_amdgcn_mfma_f32_16x16x32_bf16(afrag[kt], b0, acc0, 0, 0, 0);
        acc1 = __builtin_amdgcn_mfma_f32_16x16x32_bf16(afrag[kt], b1, acc1, 0, 0, 0);
      }
      if (q == 0) {  // rows 0..3 = reg = vocab hs*4+reg
        const int ld = t - 513;
        u64_t q0 = 0, q1 = 0;
#pragma unroll
        for (int r = 0; r < 4; ++r) {
          q0 |= (u64_t)f2bf(acc0[r] + pb_s[r]) << (16 * r);
          q1 |= (u64_t)f2bf(acc1[r] + pb_s[r]) << (16 * r);
        }
        u64_t* lq = (u64_t*)logits;
        const size_t base = ((size_t)ld * BDIM + bg * BB) * 32 + hs;
        lq[base + (size_t)n * 32] = q0;
        lq[base + (size_t)(16 + n) * 32] = q1;
      }
    }
    __syncthreads();  // drains vmcnt(0) per wave: h-stores at coherence point
    if (!last && tid == 0)
      __hip_atomic_store(&flags[bg * BB + hs], (unsigned)(t + 1), __ATOMIC_RELAXED,
                         __HIP_MEMORY_SCOPE_AGENT);
  }
}

__global__ void loss_kernel(const ushort_t* __restrict__ logits, const int* __restrict__ E,
                            float* __restrict__ partial) {
  const int t = blockIdx.x;   // 512
  const int b = threadIdx.x;  // 256
  const ushort_t* row = logits + ((size_t)t * BDIM + b) * VDIM;
  float mx = -3.0e38f;
  for (int k = 0; k < VDIM; ++k) mx = fmaxf(mx, bf2f(row[k]));
  float se = 0.f;
  for (int k = 0; k < VDIM; ++k) se += __expf(bf2f(row[k]) - mx);
  const int tgt = E[(size_t)b * (SDIM + 1) + t];
  float nll = (mx + __logf(se)) - bf2f(row[tgt]);
  float m = (tgt != 0) ? 1.f : 0.f;
  __shared__ float s1[BDIM];
  __shared__ float s0[BDIM];
  s1[b] = nll * m;
  s0[b] = m;
  __syncthreads();
  for (int s = 128; s > 0; s >>= 1) {
    if (b < s) {
      s1[b] += s1[b + s];
      s0[b] += s0[b + s];
    }
    __syncthreads();
  }
  if (b == 0) partial[t] = (s0[0] > 0.f) ? s1[0] / s0[0] : 0.f;
}

__global__ void reduce_kernel(const float* __restrict__ partial, float* __restrict__ out) {
  __shared__ float sm[SDIM];
  sm[threadIdx.x] = partial[threadIdx.x];
  __syncthreads();
  for (int s = 256; s > 0; s >>= 1) {
    if (threadIdx.x < s) sm[threadIdx.x] += sm[threadIdx.x + s];
    __syncthreads();
  }
  if (threadIdx.x == 0) out[0] = sm[0];
}

extern "C" void kernel_launch(void* const* d_in, const int* in_sizes, int n_in,
                              void* d_out, int out_size, void* d_ws, size_t ws_size,
                              hipStream_t stream) {
  const int* C_idx = (const int*)d_in[0];
  const int* E = (const int*)d_in[1];
  const float* eWih = (const float*)d_in[2];
  const float* eWhh = (const float*)d_in[3];
  const float* ebi = (const float*)d_in[4];
  const float* ebh = (const float*)d_in[5];
  const float* dWih = (const float*)d_in[6];
  const float* dWhh = (const float*)d_in[7];
  const float* dbi = (const float*)d_in[8];
  const float* dbh = (const float*)d_in[9];
  const float* pW = (const float*)d_in[10];
  const float* pb = (const float*)d_in[11];

  char* ws = (char*)d_ws;
  unsigned* flags = (unsigned*)ws;                      // 256*4 B (pad to 4096)
  u64_t* hbq = (u64_t*)(ws + 4096);                     // 2*256*512*2 = 512 KiB
  ushort_t* logits = (ushort_t*)(ws + 4096 + 524288);   // 512*256*128*2 = 32 MiB
  float* partial = (float*)(ws + 4096 + 524288 + 33554432);  // 512*4 B

  // zero flags + h buffer 0 (h(0)=0); ws is poisoned 0xAA each call
  hipMemsetAsync(d_ws, 0, 4096 + 262144, stream);
  lstm_kernel<<<256, NT, 0, stream>>>(C_idx, E, eWih, eWhh, ebi, ebh, dWih, dWhh, dbi, dbh,
                                      pW, pb, flags, hbq, logits);
  loss_kernel<<<512, 256, 0, stream>>>(logits, E, partial);
  reduce_kernel<<<1, 512, 0, stream>>>(partial, (float*)d_out);
}